// Round 19
// baseline (75.103 us; speedup 1.0000x reference)
//
#include <hip/hip_runtime.h>

// Problem constants: m=4, h=16, t=1024, d=128, MAX_REL=128.
constexpr int D_DIM = 128;
constexpr int T_Q   = 1024;
constexpr int NPE   = 257;               // 2*MAX_REL + 1 pe rows
constexpr int WAVES = 8;                 // 512-thread persistent block, 2 waves/SIMD
constexpr int BLOCK_THREADS  = WAVES * 64;
constexpr int ROWS_PER_BLOCK = 256;      // grid 256 -> one block per CU
// Each wave owns 32 rows = 2 M-tiles of 16, computed in ONE fused MFMA pass
// (shared B fragments), then two epilogue passes. One barrier total.

typedef __attribute__((ext_vector_type(8))) short short8;  // bf16x8 MFMA operand
typedef __attribute__((ext_vector_type(4))) float f32x4;   // MFMA accumulator

// readlane: uniform lane index -> SGPR broadcast, no DS/memory.
#define RL(V, SRC) __uint_as_float(__builtin_amdgcn_readlane(__float_as_uint(V), (SRC)))

// Window GEMM per wave: D[32 rows][257 pe-rows] = Q_tiles . pe^T, K=128.
// Precision: pe -> bf16 RNE; q -> hi + lo (truncation split), 2 MFMA passes.
// Layout contract (k-permutation-invariant): A row m = lane&15, B col n =
// lane&15, k-dims {32kk+8g+e} in matching slots. C/D (HW-verified m89):
// col = lane&15, row = (lane>>4)*4 + reg.
//
// r19 = r18 with PLAIN stores (NT reverted): fused dual-tile MFMA loop (each
// phi b128 read feeds 4 MFMAs; 64 reads/wave), shared phi row-256 reads,
// normal L2-path float4 out stores (L2 write aggregation smooths the drain —
// fillBuffer reaches 87% of peak through L2). Still: ONE barrier, all vmem
// loads complete before the first store, free drift.
//
// Epilogue (as r11-r15): per row c=row&3, window stored REVERSED with shift c
// into rev[w][u][p] (pads cover clip regions); out[s0..s0+3] = one aligned
// ds_read_b128; far-clip groups splat r0/r256. DS in-order per wave keeps
// write->read safe; rev is per-wave private.
__global__ __launch_bounds__(BLOCK_THREADS, 2)   // 2 waves/EU -> <=256 VGPR; need ~230
void rpe_mfma(const float* __restrict__ Q,
              const float* __restrict__ pe,
              float* __restrict__ out)
{
    __shared__ ushort phi[NPE * 128];            // 65792 B, live whole kernel
    __shared__ float  rev[WAVES][4][264];        // 33792 B, per-wave private

    const int tid = threadIdx.x;
    const int w   = tid >> 6;
    const int l   = tid & 63;
    const int n15 = l & 15;
    const int g   = l >> 4;

    // ---- stage pe -> phi as bf16 (RNE), rotated +8*(n&15); one float4 read
    //      -> one ds_write_b64 of 4 bf16 (posr0 multiple of 4, never wraps). ----
    for (int q4 = tid; q4 < NPE * 32; q4 += BLOCK_THREADS) {
        const int n  = q4 >> 5;
        const int d0 = (q4 & 31) * 4;
        const float4 f = *reinterpret_cast<const float4*>(pe + n * 128 + d0);
        const float fv[4] = {f.x, f.y, f.z, f.w};
        ushort h[4];
#pragma unroll
        for (int e = 0; e < 4; ++e) {
            const uint u = __float_as_uint(fv[e]);
            h[e] = (ushort)((u + 0x7FFFu + ((u >> 16) & 1u)) >> 16);   // RNE
        }
        const int posr0 = (d0 + 8 * (n & 15)) & 127;
        *reinterpret_cast<uint2*>(&phi[n * 128 + posr0]) = *reinterpret_cast<uint2*>(h);
    }
    __syncthreads();     // the ONLY barrier in the kernel

    const int waveRow0 = blockIdx.x * ROWS_PER_BLOCK + w * 32;

    // ---- BOTH tiles' A-fragments loaded and converted up-front: after this,
    //      the wave issues no vmem loads -> nothing drains the store queue.
    //      Lane holds row (tileRow0 + n15), dims 32kk+8g..+7. ----
    short8 ahi[2][4], alo[2][4];
#pragma unroll
    for (int i = 0; i < 2; ++i) {
        const float* qrow = Q + (size_t)(waveRow0 + 16 * i + n15) * D_DIM;
#pragma unroll
        for (int kk = 0; kk < 4; ++kk) {
            const int base = 32 * kk + 8 * g;
            const float4 a0 = *reinterpret_cast<const float4*>(qrow + base);
            const float4 a1 = *reinterpret_cast<const float4*>(qrow + base + 4);
            const float av[8] = {a0.x, a0.y, a0.z, a0.w, a1.x, a1.y, a1.z, a1.w};
#pragma unroll
            for (int e = 0; e < 8; ++e) {
                const uint u = __float_as_uint(av[e]);
                ahi[i][kk][e] = (short)(u >> 16);            // truncation: residual exact
                const float fl = av[e] - __uint_as_float(u & 0xffff0000u);
                alo[i][kk][e] = (short)(__float_as_uint(fl) >> 16);
            }
        }
    }

    // ---- FUSED MFMA main: each B fragment read once, feeds hi/lo x 2 tiles.
    //      64 b128 reads, 256 MFMA per wave. ----
    f32x4 acc[2][16];
#pragma unroll
    for (int i = 0; i < 2; ++i)
#pragma unroll
        for (int j = 0; j < 16; ++j) acc[i][j] = (f32x4){0.f, 0.f, 0.f, 0.f};

#pragma unroll
    for (int kk = 0; kk < 4; ++kk) {
        const int posr = ((32 * kk + 8 * g) + 8 * n15) & 127;
#pragma unroll
        for (int j = 0; j < 16; ++j) {
            const short8 bh = *reinterpret_cast<const short8*>(&phi[(16 * j + n15) * 128 + posr]);
            acc[0][j] = __builtin_amdgcn_mfma_f32_16x16x32_bf16(ahi[0][kk], bh, acc[0][j], 0, 0, 0);
            acc[0][j] = __builtin_amdgcn_mfma_f32_16x16x32_bf16(alo[0][kk], bh, acc[0][j], 0, 0, 0);
            acc[1][j] = __builtin_amdgcn_mfma_f32_16x16x32_bf16(ahi[1][kk], bh, acc[1][j], 0, 0, 0);
            acc[1][j] = __builtin_amdgcn_mfma_f32_16x16x32_bf16(alo[1][kk], bh, acc[1][j], 0, 0, 0);
        }
    }

    // ---- rel[256] per row, both tiles, shared phi reads: lane partial over
    //      its 32 dims of row n15, xor16+xor32 -> lane l holds row l&15. ----
    float rel_part[2] = {0.f, 0.f};
#pragma unroll
    for (int kk = 0; kk < 4; ++kk) {
        const short8 ph = *reinterpret_cast<const short8*>(&phi[256 * 128 + 32 * kk + 8 * g]);
#pragma unroll
        for (int e = 0; e < 8; ++e) {
            const float pv = __uint_as_float(((uint)(ushort)ph[e]) << 16);
#pragma unroll
            for (int i = 0; i < 2; ++i) {
                const float qv = __uint_as_float(((uint)(ushort)ahi[i][kk][e]) << 16)
                               + __uint_as_float(((uint)(ushort)alo[i][kk][e]) << 16);
                rel_part[i] = fmaf(qv, pv, rel_part[i]);
            }
        }
    }
#pragma unroll
    for (int i = 0; i < 2; ++i) {
        rel_part[i] += __shfl_xor(rel_part[i], 16, 64);
        rel_part[i] += __shfl_xor(rel_part[i], 32, 64);
    }

    // ---- two epilogue passes (static i): rows grouped by c = row&3. ----
#pragma unroll
    for (int i = 0; i < 2; ++i) {
        const int gRow0 = waveRow0 + 16 * i;
#pragma unroll
        for (int c = 0; c < 4; ++c) {
            // main spill: win[16j+n15] of row 4g+c -> rev[w][g][256 + c - 16j - n15]
#pragma unroll
            for (int j = 0; j < 16; ++j)
                rev[w][g][256 + c - 16 * j - n15] = acc[i][j][c];

            // pads + win[256]: lanes of group g serve sub-buffer u=g.
            {
                const float rel_r = __shfl(rel_part[i], 4 * g + c, 64); // rel256 row 4g+c
                const float r0_r  = __shfl(acc[i][0][c], 16 * g, 64);   // win[0]  row 4g+c
                if (n15 <= 3) {
                    if (n15 <= c) rev[w][g][n15] = rel_r;               // p in [0, c]
                } else if (n15 <= 10) {
                    const int p = 253 + n15;                            // p in [257, 263]
                    if (p >= 257 + c) rev[w][g][p] = r0_r;
                }
            }
            // DS in-order per wave + may-alias: reads below observe writes above.

#pragma unroll
            for (int u = 0; u < 4; ++u) {
                const int gRow = gRow0 + 4 * u + c;
                const int t = gRow & (T_Q - 1);                        // t === c (mod 4)
                const int ofs = 128 - t + c;
                float* orow = out + (size_t)gRow * T_Q;
                const float rr256 = RL(rel_part[i], 4 * u + c);
                const float rr0   = RL(acc[i][0][c], 16 * u);

#pragma unroll
                for (int k = 0; k < 4; ++k) {
                    const int s0 = 4 * l + 256 * k;
                    const int j0 = t + 128 - s0;          // jraw at first component
                    float4 v;
                    if (j0 <= 0) {                         // all right-clipped -> win[0]
                        v = make_float4(rr0, rr0, rr0, rr0);
                    } else if (j0 >= 259) {                // all left-clipped -> win[256]
                        v = make_float4(rr256, rr256, rr256, rr256);
                    } else {                               // one aligned b128: p0 = s0+ofs
                        v = *reinterpret_cast<const float4*>(&rev[w][u][s0 + ofs]);
                    }
                    reinterpret_cast<float4*>(orow)[l + 64 * k] = v;   // plain L2-path store
                }
            }
            // next c's spill writes cannot pass this c's gather reads (DS in-order).
        }
    }
}

extern "C" void kernel_launch(void* const* d_in, const int* in_sizes, int n_in,
                              void* d_out, int out_size, void* d_ws, size_t ws_size,
                              hipStream_t stream)
{
    const float* Q  = (const float*)d_in[0];
    // d_in[1] is K: only its shape matters (t_k = 1024), data unused.
    const float* pe = (const float*)d_in[2];
    float* out = (float*)d_out;

    const int total_rows = in_sizes[0] / D_DIM;        // m*h*t = 65536
    const int grid = total_rows / ROWS_PER_BLOCK;      // 256 -> 1 persistent block/CU
    rpe_mfma<<<grid, BLOCK_THREADS, 0, stream>>>(Q, pe, out);
}

// Round 20
// 66.356 us; speedup vs baseline: 1.1318x; 1.1318x over previous
//
#include <hip/hip_runtime.h>

// Problem constants: m=4, h=16, t=1024, d=128, MAX_REL=128.
constexpr int D_DIM = 128;
constexpr int T_Q   = 1024;
constexpr int NPE   = 257;               // 2*MAX_REL + 1 pe rows
constexpr int WAVES = 8;                 // 512-thread persistent block, 2 waves/SIMD
constexpr int BLOCK_THREADS  = WAVES * 64;
constexpr int ROWS_PER_BLOCK = 256;      // grid 256 -> one block per CU
// r20 = r15 (best, 67.6us) + nontemporal stores ONLY. Each wave owns 32 rows
// = 2 independent 16-row M-tile iterations; ONE barrier after staging.

typedef __attribute__((ext_vector_type(8))) short short8;  // bf16x8 MFMA operand
typedef __attribute__((ext_vector_type(4))) float f32x4;   // MFMA accumulator / NT store

// readlane: uniform lane index -> SGPR broadcast, no DS/memory.
#define RL(V, SRC) __uint_as_float(__builtin_amdgcn_readlane(__float_as_uint(V), (SRC)))

// Window GEMM per wave-iteration: D[16 rows][257 pe-rows] = Q_tile . pe^T, K=128.
// Precision: pe -> bf16 RNE; q -> hi + lo (truncation split), 2 MFMA passes.
// Layout contract (k-permutation-invariant): A row m = lane&15, B col n =
// lane&15, k-dims {32kk+8g+e} in matching slots. C/D (HW-verified m89):
// col = lane&15, row = (lane>>4)*4 + reg.
//
// Factorization from r15/r18/r19: unfused (two sequential tiles, ~140 VGPR)
// beats fused (230 VGPR, scheduler starvation, +7.5us); NT stores were worth
// -2.3us on the fused kernel -> apply NT to the unfused structure.
// Still: ONE barrier, all of a tile's vmem loads complete before its stores,
// free wave drift, per-wave rev buffers.
//
// Epilogue: per row c=row&3, window stored REVERSED with shift c into
// rev[w][u][p] (pads cover clip regions); out[s0..s0+3] = one aligned
// ds_read_b128; far-clip groups splat r0/r256. DS in-order per wave keeps
// write->read safe without barriers.
__global__ __launch_bounds__(BLOCK_THREADS, 2)   // 2 waves/EU -> <=256 VGPR; need ~140
void rpe_mfma(const float* __restrict__ Q,
              const float* __restrict__ pe,
              float* __restrict__ out)
{
    __shared__ ushort phi[NPE * 128];            // 65792 B, live whole kernel
    __shared__ float  rev[WAVES][4][264];        // 33792 B, per-wave private

    const int tid = threadIdx.x;
    const int w   = tid >> 6;
    const int l   = tid & 63;
    const int n15 = l & 15;
    const int g   = l >> 4;

    // ---- stage pe -> phi as bf16 (RNE), rotated +8*(n&15); one float4 read
    //      -> one ds_write_b64 of 4 bf16 (posr0 multiple of 4, never wraps). ----
    for (int q4 = tid; q4 < NPE * 32; q4 += BLOCK_THREADS) {
        const int n  = q4 >> 5;
        const int d0 = (q4 & 31) * 4;
        const float4 f = *reinterpret_cast<const float4*>(pe + n * 128 + d0);
        const float fv[4] = {f.x, f.y, f.z, f.w};
        ushort h[4];
#pragma unroll
        for (int e = 0; e < 4; ++e) {
            const uint u = __float_as_uint(fv[e]);
            h[e] = (ushort)((u + 0x7FFFu + ((u >> 16) & 1u)) >> 16);   // RNE
        }
        const int posr0 = (d0 + 8 * (n & 15)) & 127;
        *reinterpret_cast<uint2*>(&phi[n * 128 + posr0]) = *reinterpret_cast<uint2*>(h);
    }
    __syncthreads();     // the ONLY barrier in the kernel

    const int waveRow0 = blockIdx.x * ROWS_PER_BLOCK + w * 32;

    // ---- BOTH tiles' A-fragments loaded and converted up-front: after this,
    //      the wave issues no vmem loads -> nothing drains the store queue.
    //      Lane holds row (tileRow0 + n15), dims 32kk+8g..+7. ----
    short8 ahi[2][4], alo[2][4];
#pragma unroll
    for (int i = 0; i < 2; ++i) {
        const float* qrow = Q + (size_t)(waveRow0 + 16 * i + n15) * D_DIM;
#pragma unroll
        for (int kk = 0; kk < 4; ++kk) {
            const int base = 32 * kk + 8 * g;
            const float4 a0 = *reinterpret_cast<const float4*>(qrow + base);
            const float4 a1 = *reinterpret_cast<const float4*>(qrow + base + 4);
            const float av[8] = {a0.x, a0.y, a0.z, a0.w, a1.x, a1.y, a1.z, a1.w};
#pragma unroll
            for (int e = 0; e < 8; ++e) {
                const uint u = __float_as_uint(av[e]);
                ahi[i][kk][e] = (short)(u >> 16);            // truncation: residual exact
                const float fl = av[e] - __uint_as_float(u & 0xffff0000u);
                alo[i][kk][e] = (short)(__float_as_uint(fl) >> 16);
            }
        }
    }

    // ---- 2 independent iterations; waves free-drift, stores fire-and-forget. ----
#pragma unroll
    for (int i = 0; i < 2; ++i) {
        const int gRow0 = waveRow0 + 16 * i;

        // MFMA main: 16 n-tiles x 4 k-steps x 2 passes = 128 MFMA.
        f32x4 acc[16];
#pragma unroll
        for (int j = 0; j < 16; ++j) acc[j] = (f32x4){0.f, 0.f, 0.f, 0.f};

#pragma unroll
        for (int kk = 0; kk < 4; ++kk) {
            const int posr = ((32 * kk + 8 * g) + 8 * n15) & 127;
#pragma unroll
            for (int j = 0; j < 16; ++j) {
                const short8 bh = *reinterpret_cast<const short8*>(&phi[(16 * j + n15) * 128 + posr]);
                acc[j] = __builtin_amdgcn_mfma_f32_16x16x32_bf16(ahi[i][kk], bh, acc[j], 0, 0, 0);
                acc[j] = __builtin_amdgcn_mfma_f32_16x16x32_bf16(alo[i][kk], bh, acc[j], 0, 0, 0);
            }
        }

        // rel[256] per row: lane partial over its 32 dims of row n15,
        // xor16+xor32 combine g-groups -> lane l holds rel256 of row l&15.
        float rel_part = 0.f;
#pragma unroll
        for (int kk = 0; kk < 4; ++kk) {
            const short8 ph = *reinterpret_cast<const short8*>(&phi[256 * 128 + 32 * kk + 8 * g]);
#pragma unroll
            for (int e = 0; e < 8; ++e) {
                const float qv = __uint_as_float(((uint)(ushort)ahi[i][kk][e]) << 16)
                               + __uint_as_float(((uint)(ushort)alo[i][kk][e]) << 16);
                const float pv = __uint_as_float(((uint)(ushort)ph[e]) << 16);
                rel_part = fmaf(qv, pv, rel_part);
            }
        }
        rel_part += __shfl_xor(rel_part, 16, 64);
        rel_part += __shfl_xor(rel_part, 32, 64);

        // epilogue: rows grouped by c = row&3 (4 rows per group, u slot = g).
#pragma unroll
        for (int c = 0; c < 4; ++c) {
            // main spill: win[16j+n15] of row 4g+c -> rev[w][g][256 + c - 16j - n15]
#pragma unroll
            for (int j = 0; j < 16; ++j)
                rev[w][g][256 + c - 16 * j - n15] = acc[j][c];

            // pads + win[256]: lanes of group g serve sub-buffer u=g.
            {
                const float rel_r = __shfl(rel_part, 4 * g + c, 64);   // rel256 of row 4g+c
                const float r0_r  = __shfl(acc[0][c], 16 * g, 64);     // win[0]  of row 4g+c
                if (n15 <= 3) {
                    if (n15 <= c) rev[w][g][n15] = rel_r;              // p in [0, c]
                } else if (n15 <= 10) {
                    const int p = 253 + n15;                           // p in [257, 263]
                    if (p >= 257 + c) rev[w][g][p] = r0_r;
                }
            }
            // DS in-order per wave + may-alias: reads below observe writes above.

#pragma unroll
            for (int u = 0; u < 4; ++u) {
                const int gRow = gRow0 + 4 * u + c;
                const int t = gRow & (T_Q - 1);                        // t === c (mod 4)
                const int ofs = 128 - t + c;
                float* orow = out + (size_t)gRow * T_Q;
                const float rr256 = RL(rel_part, 4 * u + c);
                const float rr0   = RL(acc[0][c], 16 * u);

#pragma unroll
                for (int k = 0; k < 4; ++k) {
                    const int s0 = 4 * l + 256 * k;
                    const int j0 = t + 128 - s0;          // jraw at first component
                    f32x4 v;
                    if (j0 <= 0) {                         // all right-clipped -> win[0]
                        v = (f32x4){rr0, rr0, rr0, rr0};
                    } else if (j0 >= 259) {                // all left-clipped -> win[256]
                        v = (f32x4){rr256, rr256, rr256, rr256};
                    } else {                               // one aligned b128: p0 = s0+ofs
                        v = *reinterpret_cast<const f32x4*>(&rev[w][u][s0 + ofs]);
                    }
                    // write-once data: nontemporal keeps 268 MB out of L2.
                    __builtin_nontemporal_store(v, reinterpret_cast<f32x4*>(orow) + (l + 64 * k));
                }
            }
            // next c's spill writes cannot pass this c's gather reads (DS in-order).
        }
    }
}

extern "C" void kernel_launch(void* const* d_in, const int* in_sizes, int n_in,
                              void* d_out, int out_size, void* d_ws, size_t ws_size,
                              hipStream_t stream)
{
    const float* Q  = (const float*)d_in[0];
    // d_in[1] is K: only its shape matters (t_k = 1024), data unused.
    const float* pe = (const float*)d_in[2];
    float* out = (float*)d_out;

    const int total_rows = in_sizes[0] / D_DIM;        // m*h*t = 65536
    const int grid = total_rows / ROWS_PER_BLOCK;      // 256 -> 1 persistent block/CU
    rpe_mfma<<<grid, BLOCK_THREADS, 0, stream>>>(Q, pe, out);
}

// Round 21
// 66.020 us; speedup vs baseline: 1.1376x; 1.0051x over previous
//
#include <hip/hip_runtime.h>

// Problem constants: m=4, h=16, t=1024, d=128, MAX_REL=128.
constexpr int D_DIM = 128;
constexpr int T_Q   = 1024;
constexpr int WAVES = 4;                 // 256-thread block
constexpr int BLOCK_THREADS  = WAVES * 64;
constexpr int ROWS_PER_BLOCK = 64;       // grid 1024 -> 2 resident + 2 queued per CU
// r21 = r20's winning recipe (unfused, one barrier, all-loads-before-stores,
// NT stores, free drift) + shift pipelining: LDS squeezed to 72.4 KB so TWO
// blocks are resident per CU and two more queue behind them — a retiring
// block's store drain overlaps its replacement's staging+compute (r14's
// measured mechanism, absent from the persistent r20).

typedef __attribute__((ext_vector_type(8))) short short8;  // bf16x8 MFMA operand
typedef __attribute__((ext_vector_type(4))) float f32x4;   // MFMA accumulator / NT store

// readlane: uniform lane index -> SGPR broadcast, no DS/memory.
#define RL(V, SRC) __uint_as_float(__builtin_amdgcn_readlane(__float_as_uint(V), (SRC)))

__device__ __forceinline__ ushort f32_to_bf16_rne(float f) {
    const uint u = __float_as_uint(f);
    return (ushort)((u + 0x7FFFu + ((u >> 16) & 1u)) >> 16);
}

// Window GEMM per wave: D[16 rows][257 pe-rows] = Q_tile . pe^T, K=128.
// Precision: pe -> bf16 RNE; q -> hi + lo (truncation split), 2 MFMA passes;
// rel256 (pe row 256) computed from EXACT f32 pe (global, L2-hot).
// Layout contract (k-permutation-invariant): A row m = lane&15, B col n =
// lane&15, k-dims {32kk+8g+e} in matching slots. C/D (HW-verified m89):
// col = lane&15, row = (lane>>4)*4 + reg.
//
// LDS (72.4 KB -> 2 blocks/CU):
//   phi: bf16 [256][128] rotated +8*(n&15)   (rows 0..255 only)  = 64 KB
//   rev: bf16 [4][4][264] reversed windows                        = 8.25 KB
// Window values in rev are bf16 (middle-gather ~25% of outputs, +<=0.1 abs);
// splat constants (~75% of outputs) stay exact f32 from registers.
//
// Epilogue (as r11-r20): per row c=row&3, window stored REVERSED with shift c
// into rev[w][u][p] (p = 256+c-j; pads p in [0,c] = win[256], p in [257+c,263]
// = win[0]); out[s0..s0+3] = one aligned 8-byte DS read of 4 bf16 (p0 =
// s0+128-t+c, multiple of 4 since t === c mod 4, range [0,256]); far-clip
// groups splat f32 r0/r256. DS in-order per wave keeps write->read safe.
__global__ __launch_bounds__(BLOCK_THREADS, 2)   // 2 waves/EU -> <=256 VGPR; need ~120
void rpe_mfma(const float* __restrict__ Q,
              const float* __restrict__ pe,
              float* __restrict__ out)
{
    __shared__ ushort phi[256 * 128];            // 65536 B
    __shared__ ushort rev[WAVES][4][264];        // 8448 B

    const int tid = threadIdx.x;
    const int w   = tid >> 6;
    const int l   = tid & 63;
    const int n15 = l & 15;
    const int g   = l >> 4;

    // ---- stage pe rows 0..255 -> phi as bf16 (RNE), rotated +8*(n&15);
    //      one float4 read -> one ds_write_b64 of 4 bf16 (never wraps). ----
    for (int q4 = tid; q4 < 256 * 32; q4 += BLOCK_THREADS) {
        const int n  = q4 >> 5;
        const int d0 = (q4 & 31) * 4;
        const float4 f = *reinterpret_cast<const float4*>(pe + n * 128 + d0);
        ushort h[4] = { f32_to_bf16_rne(f.x), f32_to_bf16_rne(f.y),
                        f32_to_bf16_rne(f.z), f32_to_bf16_rne(f.w) };
        const int posr0 = (d0 + 8 * (n & 15)) & 127;
        *reinterpret_cast<uint2*>(&phi[n * 128 + posr0]) = *reinterpret_cast<uint2*>(h);
    }
    __syncthreads();     // the ONLY barrier in the kernel

    const int waveRow0 = blockIdx.x * ROWS_PER_BLOCK + w * 16;

    // ---- A-fragments loaded and converted up-front. Lane holds row
    //      (waveRow0 + n15), dims 32kk+8g..+7. ----
    const float* qrow = Q + (size_t)(waveRow0 + n15) * D_DIM;
    short8 ahi[4], alo[4];
#pragma unroll
    for (int kk = 0; kk < 4; ++kk) {
        const int base = 32 * kk + 8 * g;
        const float4 a0 = *reinterpret_cast<const float4*>(qrow + base);
        const float4 a1 = *reinterpret_cast<const float4*>(qrow + base + 4);
        const float av[8] = {a0.x, a0.y, a0.z, a0.w, a1.x, a1.y, a1.z, a1.w};
#pragma unroll
        for (int e = 0; e < 8; ++e) {
            const uint u = __float_as_uint(av[e]);
            ahi[kk][e] = (short)(u >> 16);                   // truncation: residual exact
            const float fl = av[e] - __uint_as_float(u & 0xffff0000u);
            alo[kk][e] = (short)(__float_as_uint(fl) >> 16);
        }
    }

    // ---- MFMA main: 16 n-tiles x 4 k-steps x 2 passes = 128 MFMA. ----
    f32x4 acc[16];
#pragma unroll
    for (int j = 0; j < 16; ++j) acc[j] = (f32x4){0.f, 0.f, 0.f, 0.f};

#pragma unroll
    for (int kk = 0; kk < 4; ++kk) {
        const int posr = ((32 * kk + 8 * g) + 8 * n15) & 127;
#pragma unroll
        for (int j = 0; j < 16; ++j) {
            const short8 bh = *reinterpret_cast<const short8*>(&phi[(16 * j + n15) * 128 + posr]);
            acc[j] = __builtin_amdgcn_mfma_f32_16x16x32_bf16(ahi[kk], bh, acc[j], 0, 0, 0);
            acc[j] = __builtin_amdgcn_mfma_f32_16x16x32_bf16(alo[kk], bh, acc[j], 0, 0, 0);
        }
    }

    // ---- rel[256] per row from EXACT f32 pe row 256 (global, L2-hot; these
    //      loads are issued before any store): lane partial over its 32 dims
    //      of row n15, xor16+xor32 -> lane l holds rel256 of row l&15. ----
    float rel_part = 0.f;
#pragma unroll
    for (int kk = 0; kk < 4; ++kk) {
        const float* p256 = pe + 256 * 128 + 32 * kk + 8 * g;
        const float4 pA = *reinterpret_cast<const float4*>(p256);
        const float4 pB = *reinterpret_cast<const float4*>(p256 + 4);
        const float pv[8] = {pA.x, pA.y, pA.z, pA.w, pB.x, pB.y, pB.z, pB.w};
#pragma unroll
        for (int e = 0; e < 8; ++e) {
            const float qv = __uint_as_float(((uint)(ushort)ahi[kk][e]) << 16)
                           + __uint_as_float(((uint)(ushort)alo[kk][e]) << 16);
            rel_part = fmaf(qv, pv[e], rel_part);
        }
    }
    rel_part += __shfl_xor(rel_part, 16, 64);
    rel_part += __shfl_xor(rel_part, 32, 64);

    // ---- epilogue: rows grouped by c = row&3 (4 rows per group, u slot = g).
    //      Spill reversed+shifted window as bf16 (full-lane), pads, then
    //      4 rows x 4 k-groups of {f32 splat | one 8B DS read of 4 bf16}. ----
#pragma unroll
    for (int c = 0; c < 4; ++c) {
        // main spill: win[16j+n15] of row 4g+c -> rev[w][g][256 + c - 16j - n15]
#pragma unroll
        for (int j = 0; j < 16; ++j)
            rev[w][g][256 + c - 16 * j - n15] = f32_to_bf16_rne(acc[j][c]);

        // pads + win[256]: lanes of group g serve sub-buffer u=g.
        {
            const float rel_r = __shfl(rel_part, 4 * g + c, 64);   // rel256 of row 4g+c
            const float r0_r  = __shfl(acc[0][c], 16 * g, 64);     // win[0]  of row 4g+c
            if (n15 <= 3) {
                if (n15 <= c) rev[w][g][n15] = f32_to_bf16_rne(rel_r);     // p in [0, c]
            } else if (n15 <= 10) {
                const int p = 253 + n15;                                   // p in [257, 263]
                if (p >= 257 + c) rev[w][g][p] = f32_to_bf16_rne(r0_r);
            }
        }
        // DS in-order per wave + may-alias: reads below observe writes above.

#pragma unroll
        for (int u = 0; u < 4; ++u) {
            const int gRow = waveRow0 + 4 * u + c;
            const int t = gRow & (T_Q - 1);                        // t === c (mod 4)
            const int ofs = 128 - t + c;
            float* orow = out + (size_t)gRow * T_Q;
            const float rr256 = RL(rel_part, 4 * u + c);
            const float rr0   = RL(acc[0][c], 16 * u);

#pragma unroll
            for (int k = 0; k < 4; ++k) {
                const int s0 = 4 * l + 256 * k;
                const int j0 = t + 128 - s0;          // jraw at first component
                f32x4 v;
                if (j0 <= 0) {                         // all right-clipped -> win[0] (exact f32)
                    v = (f32x4){rr0, rr0, rr0, rr0};
                } else if (j0 >= 259) {                // all left-clipped -> win[256] (exact f32)
                    v = (f32x4){rr256, rr256, rr256, rr256};
                } else {                               // one aligned 8B read: p0 = s0+ofs
                    const uint2 rr = *reinterpret_cast<const uint2*>(&rev[w][u][s0 + ofs]);
                    v = (f32x4){ __uint_as_float(rr.x << 16),
                                 __uint_as_float(rr.x & 0xffff0000u),
                                 __uint_as_float(rr.y << 16),
                                 __uint_as_float(rr.y & 0xffff0000u) };
                }
                // write-once data: nontemporal keeps 268 MB out of L2.
                __builtin_nontemporal_store(v, reinterpret_cast<f32x4*>(orow) + (l + 64 * k));
            }
        }
        // next c's spill writes cannot pass this c's gather reads (DS in-order).
    }
}

extern "C" void kernel_launch(void* const* d_in, const int* in_sizes, int n_in,
                              void* d_out, int out_size, void* d_ws, size_t ws_size,
                              hipStream_t stream)
{
    const float* Q  = (const float*)d_in[0];
    // d_in[1] is K: only its shape matters (t_k = 1024), data unused.
    const float* pe = (const float*)d_in[2];
    float* out = (float*)d_out;

    const int total_rows = in_sizes[0] / D_DIM;        // m*h*t = 65536
    const int grid = total_rows / ROWS_PER_BLOCK;      // 1024 -> 2 resident + 2 queued /CU
    rpe_mfma<<<grid, BLOCK_THREADS, 0, stream>>>(Q, pe, out);
}